// Round 2
// baseline (825.678 us; speedup 1.0000x reference)
//
#include <hip/hip_runtime.h>
#include <cstdint>
#include <cstddef>

typedef short v8s __attribute__((ext_vector_type(8)));
typedef float v4f __attribute__((ext_vector_type(4)));

__device__ inline float bs2f(short s) {
    return __uint_as_float(((unsigned int)(unsigned short)s) << 16);
}
__device__ inline short f2bs(float f) {
    unsigned int u = __float_as_uint(f);
    unsigned int r = (u + 0x7fffu + ((u >> 16) & 1u)) >> 16;  // RNE
    return (short)r;
}

#define MFMA(a, b, c) __builtin_amdgcn_mfma_f32_16x16x32_bf16((a), (b), (c), 0, 0, 0)

// ---------------------------------------------------------------- convert x
__global__ __launch_bounds__(256) void to_bf16(const float* __restrict__ X,
                                               short* __restrict__ Y, int n) {
    int i = (blockIdx.x * 256 + threadIdx.x) * 4;
    if (i < n) {
        float4 v = *(const float4*)(X + i);
        short r[4] = {f2bs(v.x), f2bs(v.y), f2bs(v.z), f2bs(v.w)};
        *(uint2*)(Y + i) = *(const uint2*)r;
    }
}

// ------------------------------------------- transpose W[K,N] -> Wt[N,K] bf16
__global__ __launch_bounds__(256) void transpose_to_bf16(const float* __restrict__ W,
                                                         short* __restrict__ Wt,
                                                         int K, int N) {
    __shared__ float tile[32][33];
    const int tx = threadIdx.x & 31, ty = threadIdx.x >> 5;  // ty 0..7
    const int n0 = blockIdx.x * 32, k0 = blockIdx.y * 32;
#pragma unroll
    for (int i = 0; i < 32; i += 8) tile[ty + i][tx] = W[(size_t)(k0 + ty + i) * N + n0 + tx];
    __syncthreads();
#pragma unroll
    for (int i = 0; i < 32; i += 8)
        Wt[(size_t)(n0 + ty + i) * K + k0 + tx] = f2bs(tile[tx][ty + i]);
}

// ----------------------------------------------------------------- GEMM B^T
// C[M,N] = A[M,K] @ B[K,N],  A bf16 row-major, Bt = B^T bf16 [N,K] row-major.
// 128x128 block tile, 4 waves (2x2), each wave 64x64 = 4x4 MFMA 16x16x32 tiles.
// out_mode: 0 = bf16 [M,N]; 1 = f32 [M,N]; 2 = bf16 transposed for V:
//   vT[((b*16+h)*128+d)*2048 + s]  where b=row>>11, s=row&2047, h=col>>7, d=col&127.
#define GSTRIDE 56  // LDS row stride in shorts: 112B (16B aligned), 2-way banks (free)

__global__ __launch_bounds__(256) void gemm_bt(const short* __restrict__ A,
                                               const short* __restrict__ Bt,
                                               void* __restrict__ C,
                                               int M, int N, int K, int out_mode) {
    __shared__ short As[128 * GSTRIDE];
    __shared__ short Bs[128 * GSTRIDE];
    const int tid = threadIdx.x;
    const int lane = tid & 63, wave = tid >> 6;
    const int l16 = lane & 15, quad = lane >> 4;
    const int wm = (wave >> 1) * 64, wn = (wave & 1) * 64;
    const int m0 = blockIdx.y * 128, n0 = blockIdx.x * 128;

    const v4f VZ = {0.f, 0.f, 0.f, 0.f};
    v4f acc[4][4];
#pragma unroll
    for (int i = 0; i < 4; i++)
#pragma unroll
        for (int j = 0; j < 4; j++) acc[i][j] = VZ;

    const int r0 = tid >> 2;           // staging row (0..63); +64 for second chunk
    const int c0 = (tid & 3) << 3;     // k-offset in shorts (0,8,16,24)

    for (int kk = 0; kk < K; kk += 32) {
        uint4 a0 = *(const uint4*)(A + (size_t)(m0 + r0) * K + kk + c0);
        uint4 a1 = *(const uint4*)(A + (size_t)(m0 + r0 + 64) * K + kk + c0);
        uint4 b0 = *(const uint4*)(Bt + (size_t)(n0 + r0) * K + kk + c0);
        uint4 b1 = *(const uint4*)(Bt + (size_t)(n0 + r0 + 64) * K + kk + c0);
        *(uint4*)(&As[r0 * GSTRIDE + c0]) = a0;
        *(uint4*)(&As[(r0 + 64) * GSTRIDE + c0]) = a1;
        *(uint4*)(&Bs[r0 * GSTRIDE + c0]) = b0;
        *(uint4*)(&Bs[(r0 + 64) * GSTRIDE + c0]) = b1;
        __syncthreads();
        v8s af[4], bfr[4];
#pragma unroll
        for (int t = 0; t < 4; t++)
            af[t] = *(const v8s*)(&As[(wm + t * 16 + l16) * GSTRIDE + quad * 8]);
#pragma unroll
        for (int t = 0; t < 4; t++)
            bfr[t] = *(const v8s*)(&Bs[(wn + t * 16 + l16) * GSTRIDE + quad * 8]);
#pragma unroll
        for (int i = 0; i < 4; i++)
#pragma unroll
            for (int j = 0; j < 4; j++) acc[i][j] = MFMA(af[i], bfr[j], acc[i][j]);
        __syncthreads();
    }

    if (out_mode == 2) {
        // transposed bf16 epilogue for V; pack 4 consecutive tokens (r) per 8B store
#pragma unroll
        for (int i = 0; i < 4; i++) {
            const int row = m0 + wm + i * 16 + quad * 4;  // token index (r=0 base)
#pragma unroll
            for (int j = 0; j < 4; j++) {
                const int col = n0 + wn + j * 16 + l16;   // h*128+d
                size_t base = ((size_t)((row >> 11) * 16 + (col >> 7)) * 128 + (col & 127)) * 2048
                              + (row & 2047);
                short pk[4];
#pragma unroll
                for (int r = 0; r < 4; r++) pk[r] = f2bs(acc[i][j][r]);
                *(uint2*)((short*)C + base) = *(const uint2*)pk;
            }
        }
        return;
    }
#pragma unroll
    for (int i = 0; i < 4; i++) {
#pragma unroll
        for (int r = 0; r < 4; r++) {
            const int row = m0 + wm + i * 16 + quad * 4 + r;
#pragma unroll
            for (int j = 0; j < 4; j++) {
                const int col = n0 + wn + j * 16 + l16;
                float v = acc[i][j][r];
                if (out_mode == 1) ((float*)C)[(size_t)row * N + col] = v;
                else ((short*)C)[(size_t)row * N + col] = f2bs(v);
            }
        }
    }
}

// ------------------------------------------------------------- RMSNorm (q)
__global__ __launch_bounds__(256) void rmsnorm_q(const short* __restrict__ X,
                                                 const float* __restrict__ g,
                                                 short* __restrict__ Y, float scale) {
    const int row = blockIdx.x * 4 + (threadIdx.x >> 6);
    const int lane = threadIdx.x & 63;
    const short* p = X + (size_t)row * 128;
    float a = bs2f(p[lane]);
    float c = bs2f(p[lane + 64]);
    float ss = a * a + c * c;
#pragma unroll
    for (int off = 1; off < 64; off <<= 1) ss += __shfl_xor(ss, off);
    float rs = rsqrtf(ss * (1.f / 128.f) + 1e-6f) * scale;
    Y[(size_t)row * 128 + lane] = f2bs(a * rs * g[lane]);
    Y[(size_t)row * 128 + lane + 64] = f2bs(c * rs * g[lane + 64]);
}

// ------------------------------------------------------------- RMSNorm (k)
__global__ __launch_bounds__(256) void rmsnorm_k(const short* __restrict__ KR,
                                                 const short* __restrict__ KN,
                                                 const float* __restrict__ g,
                                                 short* __restrict__ Y) {
    const int rh = blockIdx.x * 4 + (threadIdx.x >> 6);  // m*16+h
    const int m = rh >> 4, h = rh & 15;
    const int lane = threadIdx.x & 63;
    float a = bs2f(KR[(size_t)m * 1024 + h * 64 + lane]);
    float c = bs2f(KN[(size_t)m * 1024 + h * 64 + lane]);
    float ss = a * a + c * c;
#pragma unroll
    for (int off = 1; off < 64; off <<= 1) ss += __shfl_xor(ss, off);
    float rs = rsqrtf(ss * (1.f / 128.f) + 1e-6f);
    Y[(size_t)rh * 128 + lane] = f2bs(a * rs * g[lane]);
    Y[(size_t)rh * 128 + 64 + lane] = f2bs(c * rs * g[lane + 64]);
}

// ------------------------------------------------------ flash attention (causal)
// Q,K,O: bf16 [B,S,H,D]; V pre-transposed: vT[((b*16+h)*128+d)*S + s].
// 64 q-rows/block (16/wave), 64-key tiles.  Computes S^T = K Q^T so each lane
// owns one q-row (col = l16) for the whole softmax; P round-trips through
// wave-private LDS (no barrier) to reach A-layout for PV.
#define KSTR 136  // Ks [key][d] row stride in shorts
#define VSTR 72   // Vs [d][key] row stride
#define PSTR 72   // Ps [qrow][key] row stride

__global__ __launch_bounds__(256) void flash_attn(const short* __restrict__ Q,
                                                  const short* __restrict__ Kb,
                                                  const short* __restrict__ vT,
                                                  short* __restrict__ O, int S) {
    __shared__ short Ks[64 * KSTR];
    __shared__ short Vs[128 * VSTR];
    __shared__ short Ps[4][16 * PSTR];

    const int tid = threadIdx.x;
    const int lane = tid & 63, w = tid >> 6;
    const int l16 = lane & 15, quad = lane >> 4;
    const int bh = blockIdx.y;
    const int b = bh >> 4, h = bh & 15;
    const int qi = gridDim.x - 1 - blockIdx.x;  // heavy blocks first
    const int q0 = qi * 64;

    // Q fragment (B-operand role): lane l16 = q-row, k = d = quad*8+j
    const size_t qbase = ((size_t)(b * S + q0 + w * 16 + l16) * 16 + h) * 128;
    v8s bq[4];
#pragma unroll
    for (int kc = 0; kc < 4; kc++) bq[kc] = *(const v8s*)(Q + qbase + kc * 32 + quad * 8);

    const v4f VZ = {0.f, 0.f, 0.f, 0.f};
    v4f accO[8];
#pragma unroll
    for (int d = 0; d < 8; d++) accO[d] = VZ;
    float m_i = -1e30f, l_i = 0.f;

    // staging assignments
    const int krow = tid >> 2, kc0 = (tid & 3) * 32;  // K: 64 rows x 128 d
    const int vrow = tid >> 1, vc0 = (tid & 1) * 32;  // V: 128 d-rows x 64 keys

    for (int kt = 0; kt <= qi; ++kt) {
        const int k0 = kt * 64;
        // issue global loads before the barrier (overlap prior tile's tail)
        uint4 kr[4], vr[4];
        {
            const size_t ksrc = ((size_t)(b * S + k0 + krow) * 16 + h) * 128 + kc0;
            const size_t vsrc = ((size_t)((b * 16 + h) * 128 + vrow)) * S + k0 + vc0;
#pragma unroll
            for (int i = 0; i < 4; i++) kr[i] = *(const uint4*)(Kb + ksrc + i * 8);
#pragma unroll
            for (int i = 0; i < 4; i++) vr[i] = *(const uint4*)(vT + vsrc + i * 8);
        }
        __syncthreads();  // all waves done reading previous tile's LDS
#pragma unroll
        for (int i = 0; i < 4; i++) *(uint4*)(&Ks[krow * KSTR + kc0 + i * 8]) = kr[i];
#pragma unroll
        for (int i = 0; i < 4; i++) *(uint4*)(&Vs[vrow * VSTR + vc0 + i * 8]) = vr[i];
        __syncthreads();

        // S^T tile = K Q^T: rows = keys (quad*4+r), cols = q-rows (l16)
        v4f sc[4];
#pragma unroll
        for (int nt = 0; nt < 4; nt++) {
            v4f s = VZ;
#pragma unroll
            for (int kc = 0; kc < 4; kc++) {
                v8s ak = *(const v8s*)(&Ks[(nt * 16 + l16) * KSTR + kc * 32 + quad * 8]);
                s = MFMA(ak, bq[kc], s);
            }
            sc[nt] = s;
        }

        // causal mask: only the diagonal tile needs it
        if (kt == qi) {
            const int qrow = q0 + w * 16 + l16;
#pragma unroll
            for (int nt = 0; nt < 4; nt++)
#pragma unroll
                for (int r = 0; r < 4; r++)
                    if (k0 + nt * 16 + quad * 4 + r > qrow) sc[nt][r] = -1e30f;
        }

        // online softmax: lane owns q-row l16; keys spread over quads (+in-lane r)
        float tmax = -1e30f;
#pragma unroll
        for (int nt = 0; nt < 4; nt++)
#pragma unroll
            for (int r = 0; r < 4; r++) tmax = fmaxf(tmax, sc[nt][r]);
        tmax = fmaxf(tmax, __shfl_xor(tmax, 16));
        tmax = fmaxf(tmax, __shfl_xor(tmax, 32));
        const float mnew = fmaxf(m_i, tmax);
        const float alpha = __expf(m_i - mnew);
        m_i = mnew;
        float rsum = 0.f;
#pragma unroll
        for (int nt = 0; nt < 4; nt++) {
            short pk[4];
#pragma unroll
            for (int r = 0; r < 4; r++) {
                float p = __expf(sc[nt][r] - mnew);
                rsum += p;
                pk[r] = f2bs(p);
            }
            *(uint2*)(&Ps[w][l16 * PSTR + nt * 16 + quad * 4]) = *(const uint2*)pk;
        }
        rsum += __shfl_xor(rsum, 16);
        rsum += __shfl_xor(rsum, 32);
        l_i = l_i * alpha + rsum;

        // redistribute alpha to accO's row ownership (rows quad*4+r)
        float ar[4];
#pragma unroll
        for (int r = 0; r < 4; r++) ar[r] = __shfl(alpha, quad * 4 + r);
#pragma unroll
        for (int dt = 0; dt < 8; dt++)
#pragma unroll
            for (int r = 0; r < 4; r++) accO[dt][r] *= ar[r];

        // O += P V  (P: A-layout, wave-private LDS — no barrier needed)
        v8s ap[2];
#pragma unroll
        for (int kc2 = 0; kc2 < 2; kc2++)
            ap[kc2] = *(const v8s*)(&Ps[w][l16 * PSTR + kc2 * 32 + quad * 8]);
#pragma unroll
        for (int dt = 0; dt < 8; dt++)
#pragma unroll
            for (int kc2 = 0; kc2 < 2; kc2++) {
                v8s bv = *(const v8s*)(&Vs[(dt * 16 + l16) * VSTR + kc2 * 32 + quad * 8]);
                accO[dt] = MFMA(ap[kc2], bv, accO[dt]);
            }
    }

    float lr[4];
#pragma unroll
    for (int r = 0; r < 4; r++) lr[r] = __shfl(l_i, quad * 4 + r);
#pragma unroll
    for (int r = 0; r < 4; r++) {
        const int qg = q0 + w * 16 + quad * 4 + r;
        const float inv = 1.f / lr[r];
        const size_t obase = ((size_t)(b * S + qg) * 16 + h) * 128;
#pragma unroll
        for (int dt = 0; dt < 8; dt++) O[obase + dt * 16 + l16] = f2bs(accO[dt][r] * inv);
    }
}

// ---------------------------------------------------------------------------
extern "C" void kernel_launch(void* const* d_in, const int* in_sizes, int n_in,
                              void* d_out, int out_size, void* d_ws, size_t ws_size,
                              hipStream_t stream) {
    (void)in_sizes; (void)n_in; (void)out_size; (void)ws_size;
    const float* x   = (const float*)d_in[0];
    const float* Wq  = (const float*)d_in[1];
    const float* Wkv = (const float*)d_in[2];
    const float* Wkr = (const float*)d_in[3];
    const float* Wkn = (const float*)d_in[4];
    const float* Wv  = (const float*)d_in[5];
    const float* Wo  = (const float*)d_in[6];
    const float* gq  = (const float*)d_in[7];
    const float* gk  = (const float*)d_in[8];

    const int B = 2, S = 2048, HID = 2048, H = 16;
    const int M = B * S;  // 4096

    char* ws = (char*)d_ws;
    size_t off = 0;
    auto alloc = [&](size_t bytes) {
        char* p = ws + off;
        off += (bytes + 255) & ~(size_t)255;
        return p;
    };
    short* xb   = (short*)alloc((size_t)M * HID * 2);
    short* Wqt  = (short*)alloc((size_t)2048 * 2048 * 2);
    short* Wkvt = (short*)alloc((size_t)512 * 2048 * 2);
    short* Wkrt = (short*)alloc((size_t)1024 * 512 * 2);
    short* Wknt = (short*)alloc((size_t)1024 * 512 * 2);
    short* Wvt  = (short*)alloc((size_t)2048 * 512 * 2);
    short* Wot  = (short*)alloc((size_t)2048 * 2048 * 2);
    short* qraw = (short*)alloc((size_t)M * 2048 * 2);
    short* qb   = (short*)alloc((size_t)M * 2048 * 2);
    short* lat  = (short*)alloc((size_t)M * 512 * 2);
    short* krr  = (short*)alloc((size_t)M * 1024 * 2);
    short* knr  = (short*)alloc((size_t)M * 1024 * 2);
    short* kb   = (short*)alloc((size_t)M * 2048 * 2);
    short* vT   = (short*)alloc((size_t)M * 2048 * 2);  // [B*H][128][S]
    short* ob   = qraw;  // qraw dead after rmsnorm_q; reuse for attention output

    to_bf16<<<(M * HID) / 1024, 256, 0, stream>>>(x, xb, M * HID);
    transpose_to_bf16<<<dim3(2048 / 32, 2048 / 32), 256, 0, stream>>>(Wq, Wqt, 2048, 2048);
    transpose_to_bf16<<<dim3(512 / 32, 2048 / 32), 256, 0, stream>>>(Wkv, Wkvt, 2048, 512);
    transpose_to_bf16<<<dim3(1024 / 32, 512 / 32), 256, 0, stream>>>(Wkr, Wkrt, 512, 1024);
    transpose_to_bf16<<<dim3(1024 / 32, 512 / 32), 256, 0, stream>>>(Wkn, Wknt, 512, 1024);
    transpose_to_bf16<<<dim3(2048 / 32, 512 / 32), 256, 0, stream>>>(Wv, Wvt, 512, 2048);
    transpose_to_bf16<<<dim3(2048 / 32, 2048 / 32), 256, 0, stream>>>(Wo, Wot, 2048, 2048);

    // q = rmsnorm(x @ Wq) * gq * (1/sqrt(128))
    gemm_bt<<<dim3(2048 / 128, M / 128), 256, 0, stream>>>(xb, Wqt, qraw, M, 2048, 2048, 0);
    rmsnorm_q<<<(M * H) / 4, 256, 0, stream>>>(qraw, gq, qb, 0.08838834764831845f);

    // lat = x @ Wkv
    gemm_bt<<<dim3(512 / 128, M / 128), 256, 0, stream>>>(xb, Wkvt, lat, M, 512, 2048, 0);
    // kr / kn, then k = rmsnorm(concat)
    gemm_bt<<<dim3(1024 / 128, M / 128), 256, 0, stream>>>(lat, Wkrt, krr, M, 1024, 512, 0);
    gemm_bt<<<dim3(1024 / 128, M / 128), 256, 0, stream>>>(lat, Wknt, knr, M, 1024, 512, 0);
    rmsnorm_k<<<(M * H) / 4, 256, 0, stream>>>(krr, knr, gk, kb);
    // v = lat @ Wv, written directly transposed for flash
    gemm_bt<<<dim3(2048 / 128, M / 128), 256, 0, stream>>>(lat, Wvt, vT, M, 2048, 512, 2);

    // causal SDPA
    flash_attn<<<dim3(S / 64, B * H), 256, 0, stream>>>(qb, kb, vT, ob, S);

    // out = o @ Wo  (fp32 output)
    gemm_bt<<<dim3(2048 / 128, M / 128), 256, 0, stream>>>(ob, Wot, d_out, M, 2048, 2048, 1);
}

// Round 3
// 556.352 us; speedup vs baseline: 1.4841x; 1.4841x over previous
//
#include <hip/hip_runtime.h>
#include <cstdint>
#include <cstddef>

typedef short v8s __attribute__((ext_vector_type(8)));
typedef float v4f __attribute__((ext_vector_type(4)));

__device__ inline float bs2f(short s) {
    return __uint_as_float(((unsigned int)(unsigned short)s) << 16);
}
__device__ inline short f2bs(float f) {
    unsigned int u = __float_as_uint(f);
    unsigned int r = (u + 0x7fffu + ((u >> 16) & 1u)) >> 16;  // RNE
    return (short)r;
}

#define MFMA(a, b, c) __builtin_amdgcn_mfma_f32_16x16x32_bf16((a), (b), (c), 0, 0, 0)

// async global->LDS, 16B per lane, LDS dest = wave-uniform base + lane*16
#define GLOAD_LDS16(g, l)                                                  \
    __builtin_amdgcn_global_load_lds(                                      \
        (const __attribute__((address_space(1))) void*)(g),                \
        (__attribute__((address_space(3))) void*)(l), 16, 0, 0)

// ---------------------------------------------------------------- convert x
__global__ __launch_bounds__(256) void to_bf16(const float* __restrict__ X,
                                               short* __restrict__ Y, int n) {
    int i = (blockIdx.x * 256 + threadIdx.x) * 4;
    if (i < n) {
        float4 v = *(const float4*)(X + i);
        short r[4] = {f2bs(v.x), f2bs(v.y), f2bs(v.z), f2bs(v.w)};
        *(uint2*)(Y + i) = *(const uint2*)r;
    }
}

// ------------------------------------------- transpose W[K,N] -> Wt[N,K] bf16
__global__ __launch_bounds__(256) void transpose_to_bf16(const float* __restrict__ W,
                                                         short* __restrict__ Wt,
                                                         int K, int N) {
    __shared__ float tile[32][33];
    const int tx = threadIdx.x & 31, ty = threadIdx.x >> 5;  // ty 0..7
    const int n0 = blockIdx.x * 32, k0 = blockIdx.y * 32;
#pragma unroll
    for (int i = 0; i < 32; i += 8) tile[ty + i][tx] = W[(size_t)(k0 + ty + i) * N + n0 + tx];
    __syncthreads();
#pragma unroll
    for (int i = 0; i < 32; i += 8)
        Wt[(size_t)(n0 + ty + i) * K + k0 + tx] = f2bs(tile[tx][ty + i]);
}

// ----------------------------------------------------------------- GEMM B^T
// C[M,N] = A[M,K] @ B[K,N],  A bf16 row-major, Bt = B^T bf16 [N,K] row-major.
// out_mode: 0 = bf16 [M,N]; 1 = f32 [M,N]; 2 = bf16 transposed for V:
//   vT[((b*16+h)*128+d)*2048 + s]  where b=row>>11, s=row&2047, h=col>>7, d=col&127.
#define GSTRIDE 56  // LDS row stride in shorts

__global__ __launch_bounds__(256) void gemm_bt(const short* __restrict__ A,
                                               const short* __restrict__ Bt,
                                               void* __restrict__ C,
                                               int M, int N, int K, int out_mode) {
    __shared__ short As[128 * GSTRIDE];
    __shared__ short Bs[128 * GSTRIDE];
    const int tid = threadIdx.x;
    const int lane = tid & 63, wave = tid >> 6;
    const int l16 = lane & 15, quad = lane >> 4;
    const int wm = (wave >> 1) * 64, wn = (wave & 1) * 64;
    const int m0 = blockIdx.y * 128, n0 = blockIdx.x * 128;

    const v4f VZ = {0.f, 0.f, 0.f, 0.f};
    v4f acc[4][4];
#pragma unroll
    for (int i = 0; i < 4; i++)
#pragma unroll
        for (int j = 0; j < 4; j++) acc[i][j] = VZ;

    const int r0 = tid >> 2;           // staging row (0..63); +64 for second chunk
    const int c0 = (tid & 3) << 3;     // k-offset in shorts (0,8,16,24)

    for (int kk = 0; kk < K; kk += 32) {
        uint4 a0 = *(const uint4*)(A + (size_t)(m0 + r0) * K + kk + c0);
        uint4 a1 = *(const uint4*)(A + (size_t)(m0 + r0 + 64) * K + kk + c0);
        uint4 b0 = *(const uint4*)(Bt + (size_t)(n0 + r0) * K + kk + c0);
        uint4 b1 = *(const uint4*)(Bt + (size_t)(n0 + r0 + 64) * K + kk + c0);
        *(uint4*)(&As[r0 * GSTRIDE + c0]) = a0;
        *(uint4*)(&As[(r0 + 64) * GSTRIDE + c0]) = a1;
        *(uint4*)(&Bs[r0 * GSTRIDE + c0]) = b0;
        *(uint4*)(&Bs[(r0 + 64) * GSTRIDE + c0]) = b1;
        __syncthreads();
        v8s af[4], bfr[4];
#pragma unroll
        for (int t = 0; t < 4; t++)
            af[t] = *(const v8s*)(&As[(wm + t * 16 + l16) * GSTRIDE + quad * 8]);
#pragma unroll
        for (int t = 0; t < 4; t++)
            bfr[t] = *(const v8s*)(&Bs[(wn + t * 16 + l16) * GSTRIDE + quad * 8]);
#pragma unroll
        for (int i = 0; i < 4; i++)
#pragma unroll
            for (int j = 0; j < 4; j++) acc[i][j] = MFMA(af[i], bfr[j], acc[i][j]);
        __syncthreads();
    }

    if (out_mode == 2) {
#pragma unroll
        for (int i = 0; i < 4; i++) {
            const int row = m0 + wm + i * 16 + quad * 4;  // token index (r=0 base)
#pragma unroll
            for (int j = 0; j < 4; j++) {
                const int col = n0 + wn + j * 16 + l16;   // h*128+d
                size_t base = ((size_t)((row >> 11) * 16 + (col >> 7)) * 128 + (col & 127)) * 2048
                              + (row & 2047);
                short pk[4];
#pragma unroll
                for (int r = 0; r < 4; r++) pk[r] = f2bs(acc[i][j][r]);
                *(uint2*)((short*)C + base) = *(const uint2*)pk;
            }
        }
        return;
    }
#pragma unroll
    for (int i = 0; i < 4; i++) {
#pragma unroll
        for (int r = 0; r < 4; r++) {
            const int row = m0 + wm + i * 16 + quad * 4 + r;
#pragma unroll
            for (int j = 0; j < 4; j++) {
                const int col = n0 + wn + j * 16 + l16;
                float v = acc[i][j][r];
                if (out_mode == 1) ((float*)C)[(size_t)row * N + col] = v;
                else ((short*)C)[(size_t)row * N + col] = f2bs(v);
            }
        }
    }
}

// ------------------------------------------------------------- RMSNorm (q)
__global__ __launch_bounds__(256) void rmsnorm_q(const short* __restrict__ X,
                                                 const float* __restrict__ g,
                                                 short* __restrict__ Y, float scale) {
    const int row = blockIdx.x * 4 + (threadIdx.x >> 6);
    const int lane = threadIdx.x & 63;
    const short* p = X + (size_t)row * 128;
    float a = bs2f(p[lane]);
    float c = bs2f(p[lane + 64]);
    float ss = a * a + c * c;
#pragma unroll
    for (int off = 1; off < 64; off <<= 1) ss += __shfl_xor(ss, off);
    float rs = rsqrtf(ss * (1.f / 128.f) + 1e-6f) * scale;
    Y[(size_t)row * 128 + lane] = f2bs(a * rs * g[lane]);
    Y[(size_t)row * 128 + lane + 64] = f2bs(c * rs * g[lane + 64]);
}

// ------------------------------------------------------------- RMSNorm (k)
__global__ __launch_bounds__(256) void rmsnorm_k(const short* __restrict__ KR,
                                                 const short* __restrict__ KN,
                                                 const float* __restrict__ g,
                                                 short* __restrict__ Y) {
    const int rh = blockIdx.x * 4 + (threadIdx.x >> 6);  // m*16+h
    const int m = rh >> 4, h = rh & 15;
    const int lane = threadIdx.x & 63;
    float a = bs2f(KR[(size_t)m * 1024 + h * 64 + lane]);
    float c = bs2f(KN[(size_t)m * 1024 + h * 64 + lane]);
    float ss = a * a + c * c;
#pragma unroll
    for (int off = 1; off < 64; off <<= 1) ss += __shfl_xor(ss, off);
    float rs = rsqrtf(ss * (1.f / 128.f) + 1e-6f);
    Y[(size_t)rh * 128 + lane] = f2bs(a * rs * g[lane]);
    Y[(size_t)rh * 128 + 64 + lane] = f2bs(c * rs * g[lane + 64]);
}

// ------------------------------------------------------ flash attention (causal)
// Q,K,O: bf16 [B,S,H,D]; V pre-transposed: vT[((b*16+h)*128+d)*S + s].
// 128 q-rows/block (32/wave as 2 subtiles of 16), 64-key tiles, S^T = K Q^T.
// K/V staged via global_load_lds into packed XOR-swizzled LDS:
//   Ks: 64 rows x 256B, element chunk c (16B) stored at c ^ (row & 15)
//   Vs: 128 rows x 128B, chunk c stored at c ^ (row & 7)
#define PSTR 72   // Ps [qrow][key] row stride in shorts

__global__ __launch_bounds__(256) void flash_attn(const short* __restrict__ Q,
                                                  const short* __restrict__ Kb,
                                                  const short* __restrict__ vT,
                                                  short* __restrict__ O, int S) {
    __shared__ short Ks[64 * 128];
    __shared__ short Vs[128 * 64];
    __shared__ short Ps[4][32 * PSTR];

    const int tid = threadIdx.x;
    const int lane = tid & 63, w = tid >> 6;
    const int l16 = lane & 15, quad = lane >> 4;
    const int bh = blockIdx.y;
    const int b = bh >> 4, h = bh & 15;
    const int qi = gridDim.x - 1 - blockIdx.x;  // heavy blocks first
    const int q0 = qi * 128;
    const int wq0 = q0 + w * 32;                // this wave's first q-row

    // Q fragments (B-operand): lane l16 = q-col, quad*8+j = d
    v8s bq[2][4];
#pragma unroll
    for (int qs = 0; qs < 2; qs++) {
        const size_t qbase = ((size_t)(b * S + wq0 + qs * 16 + l16) * 16 + h) * 128;
#pragma unroll
        for (int kc = 0; kc < 4; kc++)
            bq[qs][kc] = *(const v8s*)(Q + qbase + kc * 32 + quad * 8);
    }

    const v4f VZ = {0.f, 0.f, 0.f, 0.f};
    v4f accO[2][8];
#pragma unroll
    for (int qs = 0; qs < 2; qs++)
#pragma unroll
        for (int d = 0; d < 8; d++) accO[qs][d] = VZ;
    float m_i[2] = {-1e30f, -1e30f}, l_i[2] = {0.f, 0.f};

    // staging geometry (per wave-call: 1KB = 64 lanes x 16B, contiguous LDS)
    const int krow_off = lane >> 4;                 // 0..3 within 4-row group
    const int kchunk = (lane & 15);                 // LDS chunk = lane&15
    const int vrow_off = lane >> 3;                 // 0..7 within 8-row group
    const int vchunk_g = (lane & 7) ^ (lane >> 3);  // global chunk for V slot

    for (int kt = 0; kt <= 2 * qi + 1; ++kt) {
        const int k0 = kt * 64;
        __syncthreads();  // all waves done reading previous tile's LDS
        // ---- stage K: wave w covers rows [w*16, w*16+16), 4 calls of 4 rows
#pragma unroll
        for (int j = 0; j < 4; j++) {
            const int row = w * 16 + j * 4 + krow_off;          // 0..63
            const int gch = kchunk ^ (j * 4 + krow_off);        // = kchunk ^ (row&15)
            const short* src = Kb + ((size_t)(b * S + k0 + row) * 16 + h) * 128 + gch * 8;
            GLOAD_LDS16(src, &Ks[(w * 16 + j * 4) * 128]);
        }
        // ---- stage V: wave w covers rows [w*32, w*32+32), 4 calls of 8 rows
#pragma unroll
        for (int j = 0; j < 4; j++) {
            const int row = w * 32 + j * 8 + vrow_off;          // 0..127 (d index)
            const short* src = vT + ((size_t)((b * 16 + h) * 128 + row)) * S + k0 + vchunk_g * 8;
            GLOAD_LDS16(src, &Vs[(w * 32 + j * 8) * 64]);
        }
        __syncthreads();

        if (k0 <= wq0 + 31) {  // wave-uniform: skip fully-masked tiles
            // S^T tile = K Q^T: rows = keys (quad*4+r), cols = q (l16), per qs
            v4f sc[2][4];
#pragma unroll
            for (int nt = 0; nt < 4; nt++) {
                v8s ak[4];
#pragma unroll
                for (int kc = 0; kc < 4; kc++) {
                    const int row = nt * 16 + l16;
                    const int ch = (kc * 4 + quad) ^ (row & 15);
                    ak[kc] = *(const v8s*)(&Ks[row * 128 + ch * 8]);
                }
#pragma unroll
                for (int qs = 0; qs < 2; qs++) {
                    v4f s = VZ;
#pragma unroll
                    for (int kc = 0; kc < 4; kc++) s = MFMA(ak[kc], bq[qs][kc], s);
                    sc[qs][nt] = s;
                }
            }

            // causal mask: only tiles overlapping the diagonal
            if (k0 + 63 > wq0) {
#pragma unroll
                for (int qs = 0; qs < 2; qs++) {
                    const int qrow = wq0 + qs * 16 + l16;
#pragma unroll
                    for (int nt = 0; nt < 4; nt++)
#pragma unroll
                        for (int r = 0; r < 4; r++)
                            if (k0 + nt * 16 + quad * 4 + r > qrow) sc[qs][nt][r] = -1e30f;
                }
            }

            // online softmax per q-subtile (lane owns q-col l16)
#pragma unroll
            for (int qs = 0; qs < 2; qs++) {
                float tmax = -1e30f;
#pragma unroll
                for (int nt = 0; nt < 4; nt++)
#pragma unroll
                    for (int r = 0; r < 4; r++) tmax = fmaxf(tmax, sc[qs][nt][r]);
                tmax = fmaxf(tmax, __shfl_xor(tmax, 16));
                tmax = fmaxf(tmax, __shfl_xor(tmax, 32));
                const float mnew = fmaxf(m_i[qs], tmax);
                const float alpha = __expf(m_i[qs] - mnew);
                m_i[qs] = mnew;
                float rsum = 0.f;
#pragma unroll
                for (int nt = 0; nt < 4; nt++) {
                    short pk[4];
#pragma unroll
                    for (int r = 0; r < 4; r++) {
                        float p = __expf(sc[qs][nt][r] - mnew);
                        rsum += p;
                        pk[r] = f2bs(p);
                    }
                    *(uint2*)(&Ps[w][(qs * 16 + l16) * PSTR + nt * 16 + quad * 4]) =
                        *(const uint2*)pk;
                }
                rsum += __shfl_xor(rsum, 16);
                rsum += __shfl_xor(rsum, 32);
                l_i[qs] = l_i[qs] * alpha + rsum;
                float ar[4];
#pragma unroll
                for (int r = 0; r < 4; r++) ar[r] = __shfl(alpha, quad * 4 + r);
#pragma unroll
                for (int dt = 0; dt < 8; dt++)
#pragma unroll
                    for (int r = 0; r < 4; r++) accO[qs][dt][r] *= ar[r];
            }

            // O += P V (P: A-layout from wave-private Ps — no barrier needed)
            v8s ap[2][2];
#pragma unroll
            for (int qs = 0; qs < 2; qs++)
#pragma unroll
                for (int kc2 = 0; kc2 < 2; kc2++)
                    ap[qs][kc2] =
                        *(const v8s*)(&Ps[w][(qs * 16 + l16) * PSTR + kc2 * 32 + quad * 8]);
#pragma unroll
            for (int dt = 0; dt < 8; dt++) {
#pragma unroll
                for (int kc2 = 0; kc2 < 2; kc2++) {
                    const int row = dt * 16 + l16;
                    const int ch = (kc2 * 4 + quad) ^ (row & 7);
                    v8s bv = *(const v8s*)(&Vs[row * 64 + ch * 8]);
#pragma unroll
                    for (int qs = 0; qs < 2; qs++)
                        accO[qs][dt] = MFMA(ap[qs][kc2], bv, accO[qs][dt]);
                }
            }
        }
    }

#pragma unroll
    for (int qs = 0; qs < 2; qs++) {
#pragma unroll
        for (int r = 0; r < 4; r++) {
            const int qg = wq0 + qs * 16 + quad * 4 + r;
            const float inv = 1.f / __shfl(l_i[qs], quad * 4 + r);
            const size_t obase = ((size_t)(b * S + qg) * 16 + h) * 128;
#pragma unroll
            for (int dt = 0; dt < 8; dt++)
                O[obase + dt * 16 + l16] = f2bs(accO[qs][dt][r] * inv);
        }
    }
}

// ---------------------------------------------------------------------------
extern "C" void kernel_launch(void* const* d_in, const int* in_sizes, int n_in,
                              void* d_out, int out_size, void* d_ws, size_t ws_size,
                              hipStream_t stream) {
    (void)in_sizes; (void)n_in; (void)out_size; (void)ws_size;
    const float* x   = (const float*)d_in[0];
    const float* Wq  = (const float*)d_in[1];
    const float* Wkv = (const float*)d_in[2];
    const float* Wkr = (const float*)d_in[3];
    const float* Wkn = (const float*)d_in[4];
    const float* Wv  = (const float*)d_in[5];
    const float* Wo  = (const float*)d_in[6];
    const float* gq  = (const float*)d_in[7];
    const float* gk  = (const float*)d_in[8];

    const int B = 2, S = 2048, HID = 2048, H = 16;
    const int M = B * S;  // 4096

    char* ws = (char*)d_ws;
    size_t off = 0;
    auto alloc = [&](size_t bytes) {
        char* p = ws + off;
        off += (bytes + 255) & ~(size_t)255;
        return p;
    };
    short* xb   = (short*)alloc((size_t)M * HID * 2);
    short* Wqt  = (short*)alloc((size_t)2048 * 2048 * 2);
    short* Wkvt = (short*)alloc((size_t)512 * 2048 * 2);
    short* Wkrt = (short*)alloc((size_t)1024 * 512 * 2);
    short* Wknt = (short*)alloc((size_t)1024 * 512 * 2);
    short* Wvt  = (short*)alloc((size_t)2048 * 512 * 2);
    short* Wot  = (short*)alloc((size_t)2048 * 2048 * 2);
    short* qraw = (short*)alloc((size_t)M * 2048 * 2);
    short* qb   = (short*)alloc((size_t)M * 2048 * 2);
    short* lat  = (short*)alloc((size_t)M * 512 * 2);
    short* krr  = (short*)alloc((size_t)M * 1024 * 2);
    short* knr  = (short*)alloc((size_t)M * 1024 * 2);
    short* kb   = (short*)alloc((size_t)M * 2048 * 2);
    short* vT   = (short*)alloc((size_t)M * 2048 * 2);  // [B*H][128][S]
    short* ob   = qraw;  // qraw dead after rmsnorm_q; reuse for attention output

    to_bf16<<<(M * HID) / 1024, 256, 0, stream>>>(x, xb, M * HID);
    transpose_to_bf16<<<dim3(2048 / 32, 2048 / 32), 256, 0, stream>>>(Wq, Wqt, 2048, 2048);
    transpose_to_bf16<<<dim3(512 / 32, 2048 / 32), 256, 0, stream>>>(Wkv, Wkvt, 2048, 512);
    transpose_to_bf16<<<dim3(1024 / 32, 512 / 32), 256, 0, stream>>>(Wkr, Wkrt, 512, 1024);
    transpose_to_bf16<<<dim3(1024 / 32, 512 / 32), 256, 0, stream>>>(Wkn, Wknt, 512, 1024);
    transpose_to_bf16<<<dim3(2048 / 32, 512 / 32), 256, 0, stream>>>(Wv, Wvt, 512, 2048);
    transpose_to_bf16<<<dim3(2048 / 32, 2048 / 32), 256, 0, stream>>>(Wo, Wot, 2048, 2048);

    // q = rmsnorm(x @ Wq) * gq * (1/sqrt(128))
    gemm_bt<<<dim3(2048 / 128, M / 128), 256, 0, stream>>>(xb, Wqt, qraw, M, 2048, 2048, 0);
    rmsnorm_q<<<(M * H) / 4, 256, 0, stream>>>(qraw, gq, qb, 0.08838834764831845f);

    // lat = x @ Wkv
    gemm_bt<<<dim3(512 / 128, M / 128), 256, 0, stream>>>(xb, Wkvt, lat, M, 512, 2048, 0);
    // kr / kn, then k = rmsnorm(concat)
    gemm_bt<<<dim3(1024 / 128, M / 128), 256, 0, stream>>>(lat, Wkrt, krr, M, 1024, 512, 0);
    gemm_bt<<<dim3(1024 / 128, M / 128), 256, 0, stream>>>(lat, Wknt, knr, M, 1024, 512, 0);
    rmsnorm_k<<<(M * H) / 4, 256, 0, stream>>>(krr, knr, gk, kb);
    // v = lat @ Wv, written directly transposed for flash
    gemm_bt<<<dim3(2048 / 128, M / 128), 256, 0, stream>>>(lat, Wvt, vT, M, 2048, 512, 2);

    // causal SDPA: 128 q-rows per block
    flash_attn<<<dim3(S / 128, B * H), 256, 0, stream>>>(qb, kb, vT, ob, S);

    // out = o @ Wo  (fp32 output)
    gemm_bt<<<dim3(2048 / 128, M / 128), 256, 0, stream>>>(ob, Wot, d_out, M, 2048, 2048, 1);
}

// Round 4
// 497.513 us; speedup vs baseline: 1.6596x; 1.1183x over previous
//
#include <hip/hip_runtime.h>
#include <cstdint>
#include <cstddef>

typedef short v8s __attribute__((ext_vector_type(8)));
typedef float v4f __attribute__((ext_vector_type(4)));

__device__ inline float bs2f(short s) {
    return __uint_as_float(((unsigned int)(unsigned short)s) << 16);
}
__device__ inline short f2bs(float f) {
    unsigned int u = __float_as_uint(f);
    unsigned int r = (u + 0x7fffu + ((u >> 16) & 1u)) >> 16;  // RNE
    return (short)r;
}

#define MFMA(a, b, c) __builtin_amdgcn_mfma_f32_16x16x32_bf16((a), (b), (c), 0, 0, 0)

// async global->LDS, 16B per lane, LDS dest = wave-uniform base + lane*16
#define GLOAD_LDS16(g, l)                                                  \
    __builtin_amdgcn_global_load_lds(                                      \
        (const __attribute__((address_space(1))) void*)(g),                \
        (__attribute__((address_space(3))) void*)(l), 16, 0, 0)

// ---------------------------------------------------------------- convert x
__global__ __launch_bounds__(256) void to_bf16(const float* __restrict__ X,
                                               short* __restrict__ Y, int n) {
    int i = (blockIdx.x * 256 + threadIdx.x) * 4;
    if (i < n) {
        float4 v = *(const float4*)(X + i);
        short r[4] = {f2bs(v.x), f2bs(v.y), f2bs(v.z), f2bs(v.w)};
        *(uint2*)(Y + i) = *(const uint2*)r;
    }
}

// ------------------------------------------- transpose W[K,N] -> Wt[N,K] bf16
__global__ __launch_bounds__(256) void transpose_to_bf16(const float* __restrict__ W,
                                                         short* __restrict__ Wt,
                                                         int K, int N) {
    __shared__ float tile[32][33];
    const int tx = threadIdx.x & 31, ty = threadIdx.x >> 5;  // ty 0..7
    const int n0 = blockIdx.x * 32, k0 = blockIdx.y * 32;
#pragma unroll
    for (int i = 0; i < 32; i += 8) tile[ty + i][tx] = W[(size_t)(k0 + ty + i) * N + n0 + tx];
    __syncthreads();
#pragma unroll
    for (int i = 0; i < 32; i += 8)
        Wt[(size_t)(n0 + ty + i) * K + k0 + tx] = f2bs(tile[tx][ty + i]);
}

// ----------------------------------------------------------------- GEMM B^T
// C = A[M,K] @ B[K,N], Bt = B^T [N,K] bf16. 128x128 tile, 4 waves, 4x4 MFMA
// 16x16x32 per wave. Staging via global_load_lds (16B), packed LDS 128x32
// shorts per tile, XOR swizzle: chunk c of row r stored at slot c^((r>>1)&3).
// mode 0: bf16 C0[M,N]
// mode 1: f32  C0[M,N]
// mode 2: col<2048 -> C0 bf16 ld 2048 ; else -> C1 bf16 ld 512 (col-2048)
// mode 3: col<1024 -> C0 ld 1024 ; col<2048 -> C1 ld 1024 ; else transposed V
//         write to C2: C2[((row>>11)*16 + (c>>7))*128 + (c&127)][row&2047], c=col-2048
__global__ __launch_bounds__(256) void gemm_bt(const short* __restrict__ A,
                                               const short* __restrict__ Bt,
                                               void* __restrict__ C0,
                                               void* __restrict__ C1,
                                               void* __restrict__ C2,
                                               int M, int N, int K, int mode) {
    __shared__ short As[128 * 32];
    __shared__ short Bs[128 * 32];
    const int tid = threadIdx.x;
    const int lane = tid & 63, wave = tid >> 6;
    const int l16 = lane & 15, quad = lane >> 4;
    const int wm = (wave >> 1) * 64, wn = (wave & 1) * 64;
    const int m0 = blockIdx.y * 128, n0 = blockIdx.x * 128;

    const v4f VZ = {0.f, 0.f, 0.f, 0.f};
    v4f acc[4][4];
#pragma unroll
    for (int i = 0; i < 4; i++)
#pragma unroll
        for (int j = 0; j < 4; j++) acc[i][j] = VZ;

    // staging: wave covers rows [wave*32, wave*32+32), two 16-row calls each
    const int r0 = wave * 32 + (lane >> 2);       // rows for call 0
    const int r1 = r0 + 16;                       // rows for call 1
    const int c0 = ((lane & 3) ^ ((r0 >> 1) & 3)) * 8;
    const int c1 = ((lane & 3) ^ ((r1 >> 1) & 3)) * 8;
    const short* aSrc0 = A + (size_t)(m0 + r0) * K + c0;
    const short* aSrc1 = A + (size_t)(m0 + r1) * K + c1;
    const short* bSrc0 = Bt + (size_t)(n0 + r0) * K + c0;
    const short* bSrc1 = Bt + (size_t)(n0 + r1) * K + c1;
    short* const ldsA0 = &As[(wave * 32) * 32];
    short* const ldsA1 = &As[(wave * 32 + 16) * 32];
    short* const ldsB0 = &Bs[(wave * 32) * 32];
    short* const ldsB1 = &Bs[(wave * 32 + 16) * 32];

    for (int kk = 0; kk < K; kk += 32) {
        __syncthreads();  // previous iteration's fragment reads complete
        GLOAD_LDS16(aSrc0 + kk, ldsA0);
        GLOAD_LDS16(aSrc1 + kk, ldsA1);
        GLOAD_LDS16(bSrc0 + kk, ldsB0);
        GLOAD_LDS16(bSrc1 + kk, ldsB1);
        __syncthreads();  // drain global_load_lds

        v8s af[4], bfr[4];
#pragma unroll
        for (int t = 0; t < 4; t++) {
            const int ra = wm + t * 16 + l16;
            af[t] = *(const v8s*)(&As[ra * 32 + ((quad ^ ((ra >> 1) & 3)) * 8)]);
        }
#pragma unroll
        for (int t = 0; t < 4; t++) {
            const int rb = wn + t * 16 + l16;
            bfr[t] = *(const v8s*)(&Bs[rb * 32 + ((quad ^ ((rb >> 1) & 3)) * 8)]);
        }
#pragma unroll
        for (int i = 0; i < 4; i++)
#pragma unroll
            for (int j = 0; j < 4; j++) acc[i][j] = MFMA(af[i], bfr[j], acc[i][j]);
    }

    if (mode == 3 && n0 >= 2048) {
        // transposed bf16 V epilogue; pack 4 consecutive tokens per 8B store
        short* C = (short*)C2;
#pragma unroll
        for (int i = 0; i < 4; i++) {
            const int row = m0 + wm + i * 16 + quad * 4;  // token (r=0 base)
#pragma unroll
            for (int j = 0; j < 4; j++) {
                const int col = n0 - 2048 + wn + j * 16 + l16;  // h*128+d
                size_t base = ((size_t)((row >> 11) * 16 + (col >> 7)) * 128 + (col & 127)) * 2048
                              + (row & 2047);
                short pk[4];
#pragma unroll
                for (int r = 0; r < 4; r++) pk[r] = f2bs(acc[i][j][r]);
                *(uint2*)(C + base) = *(const uint2*)pk;
            }
        }
        return;
    }

    // block-uniform routing for the flat epilogues
    void* Cb = C0;
    int ld = N, coff = 0;
    if (mode == 2) {
        if (n0 < 2048) { Cb = C0; ld = 2048; coff = 0; }
        else           { Cb = C1; ld = 512;  coff = 2048; }
    } else if (mode == 3) {
        if (n0 < 1024) { Cb = C0; ld = 1024; coff = 0; }
        else           { Cb = C1; ld = 1024; coff = 1024; }
    }
#pragma unroll
    for (int i = 0; i < 4; i++) {
#pragma unroll
        for (int r = 0; r < 4; r++) {
            const int row = m0 + wm + i * 16 + quad * 4 + r;
#pragma unroll
            for (int j = 0; j < 4; j++) {
                const int col = n0 - coff + wn + j * 16 + l16;
                float v = acc[i][j][r];
                if (mode == 1) ((float*)Cb)[(size_t)row * ld + col] = v;
                else ((short*)Cb)[(size_t)row * ld + col] = f2bs(v);
            }
        }
    }
}

// ------------------------------------------------------------- RMSNorm (q)
__global__ __launch_bounds__(256) void rmsnorm_q(const short* __restrict__ X,
                                                 const float* __restrict__ g,
                                                 short* __restrict__ Y, float scale) {
    const int row = blockIdx.x * 4 + (threadIdx.x >> 6);
    const int lane = threadIdx.x & 63;
    const short* p = X + (size_t)row * 128;
    float a = bs2f(p[lane]);
    float c = bs2f(p[lane + 64]);
    float ss = a * a + c * c;
#pragma unroll
    for (int off = 1; off < 64; off <<= 1) ss += __shfl_xor(ss, off);
    float rs = rsqrtf(ss * (1.f / 128.f) + 1e-6f) * scale;
    Y[(size_t)row * 128 + lane] = f2bs(a * rs * g[lane]);
    Y[(size_t)row * 128 + lane + 64] = f2bs(c * rs * g[lane + 64]);
}

// ------------------------------------------------------------- RMSNorm (k)
__global__ __launch_bounds__(256) void rmsnorm_k(const short* __restrict__ KR,
                                                 const short* __restrict__ KN,
                                                 const float* __restrict__ g,
                                                 short* __restrict__ Y) {
    const int rh = blockIdx.x * 4 + (threadIdx.x >> 6);  // m*16+h
    const int m = rh >> 4, h = rh & 15;
    const int lane = threadIdx.x & 63;
    float a = bs2f(KR[(size_t)m * 1024 + h * 64 + lane]);
    float c = bs2f(KN[(size_t)m * 1024 + h * 64 + lane]);
    float ss = a * a + c * c;
#pragma unroll
    for (int off = 1; off < 64; off <<= 1) ss += __shfl_xor(ss, off);
    float rs = rsqrtf(ss * (1.f / 128.f) + 1e-6f);
    Y[(size_t)rh * 128 + lane] = f2bs(a * rs * g[lane]);
    Y[(size_t)rh * 128 + 64 + lane] = f2bs(c * rs * g[lane + 64]);
}

// ------------------------------------------------------ flash attention (causal)
// Q,K,O: bf16 [B,S,H,D]; V pre-transposed: vT[((b*16+h)*128+d)*S + s].
// 128 q-rows/block (32/wave as 2 subtiles of 16), 64-key tiles, S^T = K Q^T.
// log2(e) folded into q scale -> exp2f for softmax.
#define PSTR 72   // Ps [qrow][key] row stride in shorts

__global__ __launch_bounds__(256) void flash_attn(const short* __restrict__ Q,
                                                  const short* __restrict__ Kb,
                                                  const short* __restrict__ vT,
                                                  short* __restrict__ O, int S) {
    __shared__ short Ks[64 * 128];
    __shared__ short Vs[128 * 64];
    __shared__ short Ps[4][32 * PSTR];

    const int tid = threadIdx.x;
    const int lane = tid & 63, w = tid >> 6;
    const int l16 = lane & 15, quad = lane >> 4;
    const int bh = blockIdx.y;
    const int b = bh >> 4, h = bh & 15;
    const int qi = gridDim.x - 1 - blockIdx.x;  // heavy blocks first
    const int q0 = qi * 128;
    const int wq0 = q0 + w * 32;                // this wave's first q-row

    v8s bq[2][4];
#pragma unroll
    for (int qs = 0; qs < 2; qs++) {
        const size_t qbase = ((size_t)(b * S + wq0 + qs * 16 + l16) * 16 + h) * 128;
#pragma unroll
        for (int kc = 0; kc < 4; kc++)
            bq[qs][kc] = *(const v8s*)(Q + qbase + kc * 32 + quad * 8);
    }

    const v4f VZ = {0.f, 0.f, 0.f, 0.f};
    v4f accO[2][8];
#pragma unroll
    for (int qs = 0; qs < 2; qs++)
#pragma unroll
        for (int d = 0; d < 8; d++) accO[qs][d] = VZ;
    float m_i[2] = {-1e30f, -1e30f}, l_i[2] = {0.f, 0.f};

    const int krow_off = lane >> 4;
    const int kchunk = (lane & 15);
    const int vrow_off = lane >> 3;
    const int vchunk_g = (lane & 7) ^ (lane >> 3);

    for (int kt = 0; kt <= 2 * qi + 1; ++kt) {
        const int k0 = kt * 64;
        __syncthreads();
#pragma unroll
        for (int j = 0; j < 4; j++) {
            const int row = w * 16 + j * 4 + krow_off;
            const int gch = kchunk ^ (j * 4 + krow_off);
            const short* src = Kb + ((size_t)(b * S + k0 + row) * 16 + h) * 128 + gch * 8;
            GLOAD_LDS16(src, &Ks[(w * 16 + j * 4) * 128]);
        }
#pragma unroll
        for (int j = 0; j < 4; j++) {
            const int row = w * 32 + j * 8 + vrow_off;
            const short* src = vT + ((size_t)((b * 16 + h) * 128 + row)) * S + k0 + vchunk_g * 8;
            GLOAD_LDS16(src, &Vs[(w * 32 + j * 8) * 64]);
        }
        __syncthreads();

        if (k0 <= wq0 + 31) {  // wave-uniform: skip fully-masked tiles
            v4f sc[2][4];
#pragma unroll
            for (int nt = 0; nt < 4; nt++) {
                v8s ak[4];
#pragma unroll
                for (int kc = 0; kc < 4; kc++) {
                    const int row = nt * 16 + l16;
                    const int ch = (kc * 4 + quad) ^ (row & 15);
                    ak[kc] = *(const v8s*)(&Ks[row * 128 + ch * 8]);
                }
#pragma unroll
                for (int qs = 0; qs < 2; qs++) {
                    v4f s = VZ;
#pragma unroll
                    for (int kc = 0; kc < 4; kc++) s = MFMA(ak[kc], bq[qs][kc], s);
                    sc[qs][nt] = s;
                }
            }

            if (k0 + 63 > wq0) {  // diagonal tiles only
#pragma unroll
                for (int qs = 0; qs < 2; qs++) {
                    const int qrow = wq0 + qs * 16 + l16;
#pragma unroll
                    for (int nt = 0; nt < 4; nt++)
#pragma unroll
                        for (int r = 0; r < 4; r++)
                            if (k0 + nt * 16 + quad * 4 + r > qrow) sc[qs][nt][r] = -1e30f;
                }
            }

#pragma unroll
            for (int qs = 0; qs < 2; qs++) {
                float tmax = -1e30f;
#pragma unroll
                for (int nt = 0; nt < 4; nt++)
#pragma unroll
                    for (int r = 0; r < 4; r++) tmax = fmaxf(tmax, sc[qs][nt][r]);
                tmax = fmaxf(tmax, __shfl_xor(tmax, 16));
                tmax = fmaxf(tmax, __shfl_xor(tmax, 32));
                const float mnew = fmaxf(m_i[qs], tmax);
                const float alpha = exp2f(m_i[qs] - mnew);
                m_i[qs] = mnew;
                float rsum = 0.f;
#pragma unroll
                for (int nt = 0; nt < 4; nt++) {
                    short pk[4];
#pragma unroll
                    for (int r = 0; r < 4; r++) {
                        float p = exp2f(sc[qs][nt][r] - mnew);
                        rsum += p;
                        pk[r] = f2bs(p);
                    }
                    *(uint2*)(&Ps[w][(qs * 16 + l16) * PSTR + nt * 16 + quad * 4]) =
                        *(const uint2*)pk;
                }
                rsum += __shfl_xor(rsum, 16);
                rsum += __shfl_xor(rsum, 32);
                l_i[qs] = l_i[qs] * alpha + rsum;
                float ar[4];
#pragma unroll
                for (int r = 0; r < 4; r++) ar[r] = __shfl(alpha, quad * 4 + r);
#pragma unroll
                for (int dt = 0; dt < 8; dt++)
#pragma unroll
                    for (int r = 0; r < 4; r++) accO[qs][dt][r] *= ar[r];
            }

            v8s ap[2][2];
#pragma unroll
            for (int qs = 0; qs < 2; qs++)
#pragma unroll
                for (int kc2 = 0; kc2 < 2; kc2++)
                    ap[qs][kc2] =
                        *(const v8s*)(&Ps[w][(qs * 16 + l16) * PSTR + kc2 * 32 + quad * 8]);
#pragma unroll
            for (int dt = 0; dt < 8; dt++) {
#pragma unroll
                for (int kc2 = 0; kc2 < 2; kc2++) {
                    const int row = dt * 16 + l16;
                    const int ch = (kc2 * 4 + quad) ^ (row & 7);
                    v8s bv = *(const v8s*)(&Vs[row * 64 + ch * 8]);
#pragma unroll
                    for (int qs = 0; qs < 2; qs++)
                        accO[qs][dt] = MFMA(ap[qs][kc2], bv, accO[qs][dt]);
                }
            }
        }
    }

#pragma unroll
    for (int qs = 0; qs < 2; qs++) {
#pragma unroll
        for (int r = 0; r < 4; r++) {
            const int qg = wq0 + qs * 16 + quad * 4 + r;
            const float inv = 1.f / __shfl(l_i[qs], quad * 4 + r);
            const size_t obase = ((size_t)(b * S + qg) * 16 + h) * 128;
#pragma unroll
            for (int dt = 0; dt < 8; dt++)
                O[obase + dt * 16 + l16] = f2bs(accO[qs][dt][r] * inv);
        }
    }
}

// ---------------------------------------------------------------------------
extern "C" void kernel_launch(void* const* d_in, const int* in_sizes, int n_in,
                              void* d_out, int out_size, void* d_ws, size_t ws_size,
                              hipStream_t stream) {
    (void)in_sizes; (void)n_in; (void)out_size; (void)ws_size;
    const float* x   = (const float*)d_in[0];
    const float* Wq  = (const float*)d_in[1];
    const float* Wkv = (const float*)d_in[2];
    const float* Wkr = (const float*)d_in[3];
    const float* Wkn = (const float*)d_in[4];
    const float* Wv  = (const float*)d_in[5];
    const float* Wo  = (const float*)d_in[6];
    const float* gq  = (const float*)d_in[7];
    const float* gk  = (const float*)d_in[8];

    const int B = 2, S = 2048, HID = 2048, H = 16;
    const int M = B * S;  // 4096

    char* ws = (char*)d_ws;
    size_t off = 0;
    auto alloc = [&](size_t bytes) {
        char* p = ws + off;
        off += (bytes + 255) & ~(size_t)255;
        return p;
    };
    short* xb   = (short*)alloc((size_t)M * HID * 2);
    short* WtA  = (short*)alloc((size_t)2560 * 2048 * 2);  // [Wq^T | Wkv^T]
    short* WtB  = (short*)alloc((size_t)4096 * 512 * 2);   // [Wkr^T | Wkn^T | Wv^T]
    short* Wot  = (short*)alloc((size_t)2048 * 2048 * 2);
    short* qraw = (short*)alloc((size_t)M * 2048 * 2);
    short* qb   = (short*)alloc((size_t)M * 2048 * 2);
    short* lat  = (short*)alloc((size_t)M * 512 * 2);
    short* krr  = (short*)alloc((size_t)M * 1024 * 2);
    short* knr  = (short*)alloc((size_t)M * 1024 * 2);
    short* kb   = (short*)alloc((size_t)M * 2048 * 2);
    short* vT   = (short*)alloc((size_t)M * 2048 * 2);  // [B*H][128][S]
    short* ob   = qraw;  // qraw dead after rmsnorm_q; reuse for attention output

    to_bf16<<<(M * HID) / 1024, 256, 0, stream>>>(x, xb, M * HID);
    transpose_to_bf16<<<dim3(64, 64), 256, 0, stream>>>(Wq, WtA, 2048, 2048);
    transpose_to_bf16<<<dim3(16, 64), 256, 0, stream>>>(Wkv, WtA + (size_t)2048 * 2048, 2048, 512);
    transpose_to_bf16<<<dim3(32, 16), 256, 0, stream>>>(Wkr, WtB, 512, 1024);
    transpose_to_bf16<<<dim3(32, 16), 256, 0, stream>>>(Wkn, WtB + (size_t)1024 * 512, 512, 1024);
    transpose_to_bf16<<<dim3(64, 16), 256, 0, stream>>>(Wv, WtB + (size_t)2048 * 512, 512, 2048);
    transpose_to_bf16<<<dim3(64, 64), 256, 0, stream>>>(Wo, Wot, 2048, 2048);

    // GEMM-A: x @ [Wq | Wkv] -> qraw (bf16) + lat (bf16)
    gemm_bt<<<dim3(2560 / 128, M / 128), 256, 0, stream>>>(
        xb, WtA, qraw, lat, nullptr, M, 2560, 2048, 2);
    // q = rmsnorm(qraw) * gq * (1/sqrt(128)) * log2(e)  [exp2 softmax domain]
    rmsnorm_q<<<(M * H) / 4, 256, 0, stream>>>(
        qraw, gq, qb, 0.08838834764831845f * 1.4426950408889634f);

    // GEMM-B: lat @ [Wkr | Wkn | Wv] -> krr, knr, vT(transposed)
    gemm_bt<<<dim3(4096 / 128, M / 128), 256, 0, stream>>>(
        lat, WtB, krr, knr, vT, M, 4096, 512, 3);
    rmsnorm_k<<<(M * H) / 4, 256, 0, stream>>>(krr, knr, gk, kb);

    // causal SDPA: 128 q-rows per block
    flash_attn<<<dim3(S / 128, B * H), 256, 0, stream>>>(qb, kb, vT, ob, S);

    // GEMM-C: out = o @ Wo (fp32)
    gemm_bt<<<dim3(2048 / 128, M / 128), 256, 0, stream>>>(
        ob, Wot, d_out, nullptr, nullptr, M, 2048, 2048, 1);
}

// Round 5
// 495.096 us; speedup vs baseline: 1.6677x; 1.0049x over previous
//
#include <hip/hip_runtime.h>
#include <cstdint>
#include <cstddef>

typedef short v8s __attribute__((ext_vector_type(8)));
typedef float v4f __attribute__((ext_vector_type(4)));

__device__ inline float bs2f(short s) {
    return __uint_as_float(((unsigned int)(unsigned short)s) << 16);
}
__device__ inline short f2bs(float f) {
    unsigned int u = __float_as_uint(f);
    unsigned int r = (u + 0x7fffu + ((u >> 16) & 1u)) >> 16;  // RNE
    return (short)r;
}

#define MFMA(a, b, c) __builtin_amdgcn_mfma_f32_16x16x32_bf16((a), (b), (c), 0, 0, 0)

// async global->LDS, 16B per lane, LDS dest = wave-uniform base + lane*16
#define GLOAD_LDS16(g, l)                                                  \
    __builtin_amdgcn_global_load_lds(                                      \
        (const __attribute__((address_space(1))) void*)(g),                \
        (__attribute__((address_space(3))) void*)(l), 16, 0, 0)

// ---------------------------------------------------------------- convert x
__global__ __launch_bounds__(256) void to_bf16(const float* __restrict__ X,
                                               short* __restrict__ Y, int n) {
    int i = (blockIdx.x * 256 + threadIdx.x) * 4;
    if (i < n) {
        float4 v = *(const float4*)(X + i);
        short r[4] = {f2bs(v.x), f2bs(v.y), f2bs(v.z), f2bs(v.w)};
        *(uint2*)(Y + i) = *(const uint2*)r;
    }
}

// ------------------------------------------- transpose W[K,N] -> Wt[N,K] bf16
__global__ __launch_bounds__(256) void transpose_to_bf16(const float* __restrict__ W,
                                                         short* __restrict__ Wt,
                                                         int K, int N) {
    __shared__ float tile[32][33];
    const int tx = threadIdx.x & 31, ty = threadIdx.x >> 5;  // ty 0..7
    const int n0 = blockIdx.x * 32, k0 = blockIdx.y * 32;
#pragma unroll
    for (int i = 0; i < 32; i += 8) tile[ty + i][tx] = W[(size_t)(k0 + ty + i) * N + n0 + tx];
    __syncthreads();
#pragma unroll
    for (int i = 0; i < 32; i += 8)
        Wt[(size_t)(n0 + ty + i) * K + k0 + tx] = f2bs(tile[tx][ty + i]);
}

// ----------------------------------------------------------------- GEMM B^T
// C = A[M,K] @ B[K,N], Bt = B^T [N,K] bf16. 128x128 tile, 4 waves, 4x4 MFMA
// 16x16x32 per wave. Staging via global_load_lds (16B), packed LDS 128x32
// shorts per tile, XOR swizzle: chunk c of row r stored at slot c^((r>>1)&3).
// mode 0: bf16 C0[M,N]
// mode 1: f32  C0[M,N]
// mode 2: col<2048 -> C0 bf16 ld 2048 ; else -> C1 bf16 ld 512 (col-2048)
// mode 3: col<1024 -> C0 ld 1024 ; col<2048 -> C1 ld 1024 ; else transposed V
//         write to C2: C2[((row>>11)*16 + (c>>7))*128 + (c&127)][row&2047], c=col-2048
__global__ __launch_bounds__(256) void gemm_bt(const short* __restrict__ A,
                                               const short* __restrict__ Bt,
                                               void* __restrict__ C0,
                                               void* __restrict__ C1,
                                               void* __restrict__ C2,
                                               int M, int N, int K, int mode) {
    __shared__ short As[128 * 32];
    __shared__ short Bs[128 * 32];
    const int tid = threadIdx.x;
    const int lane = tid & 63, wave = tid >> 6;
    const int l16 = lane & 15, quad = lane >> 4;
    const int wm = (wave >> 1) * 64, wn = (wave & 1) * 64;
    const int m0 = blockIdx.y * 128, n0 = blockIdx.x * 128;

    const v4f VZ = {0.f, 0.f, 0.f, 0.f};
    v4f acc[4][4];
#pragma unroll
    for (int i = 0; i < 4; i++)
#pragma unroll
        for (int j = 0; j < 4; j++) acc[i][j] = VZ;

    // staging: wave covers rows [wave*32, wave*32+32), two 16-row calls each
    const int r0 = wave * 32 + (lane >> 2);       // rows for call 0
    const int r1 = r0 + 16;                       // rows for call 1
    const int c0 = ((lane & 3) ^ ((r0 >> 1) & 3)) * 8;
    const int c1 = ((lane & 3) ^ ((r1 >> 1) & 3)) * 8;
    const short* aSrc0 = A + (size_t)(m0 + r0) * K + c0;
    const short* aSrc1 = A + (size_t)(m0 + r1) * K + c1;
    const short* bSrc0 = Bt + (size_t)(n0 + r0) * K + c0;
    const short* bSrc1 = Bt + (size_t)(n0 + r1) * K + c1;
    short* const ldsA0 = &As[(wave * 32) * 32];
    short* const ldsA1 = &As[(wave * 32 + 16) * 32];
    short* const ldsB0 = &Bs[(wave * 32) * 32];
    short* const ldsB1 = &Bs[(wave * 32 + 16) * 32];

    for (int kk = 0; kk < K; kk += 32) {
        __syncthreads();  // previous iteration's fragment reads complete
        GLOAD_LDS16(aSrc0 + kk, ldsA0);
        GLOAD_LDS16(aSrc1 + kk, ldsA1);
        GLOAD_LDS16(bSrc0 + kk, ldsB0);
        GLOAD_LDS16(bSrc1 + kk, ldsB1);
        __syncthreads();  // drain global_load_lds

        v8s af[4], bfr[4];
#pragma unroll
        for (int t = 0; t < 4; t++) {
            const int ra = wm + t * 16 + l16;
            af[t] = *(const v8s*)(&As[ra * 32 + ((quad ^ ((ra >> 1) & 3)) * 8)]);
        }
#pragma unroll
        for (int t = 0; t < 4; t++) {
            const int rb = wn + t * 16 + l16;
            bfr[t] = *(const v8s*)(&Bs[rb * 32 + ((quad ^ ((rb >> 1) & 3)) * 8)]);
        }
#pragma unroll
        for (int i = 0; i < 4; i++)
#pragma unroll
            for (int j = 0; j < 4; j++) acc[i][j] = MFMA(af[i], bfr[j], acc[i][j]);
    }

    if (mode == 3 && n0 >= 2048) {
        // transposed bf16 V epilogue; pack 4 consecutive tokens per 8B store
        short* C = (short*)C2;
#pragma unroll
        for (int i = 0; i < 4; i++) {
            const int row = m0 + wm + i * 16 + quad * 4;  // token (r=0 base)
#pragma unroll
            for (int j = 0; j < 4; j++) {
                const int col = n0 - 2048 + wn + j * 16 + l16;  // h*128+d
                size_t base = ((size_t)((row >> 11) * 16 + (col >> 7)) * 128 + (col & 127)) * 2048
                              + (row & 2047);
                short pk[4];
#pragma unroll
                for (int r = 0; r < 4; r++) pk[r] = f2bs(acc[i][j][r]);
                *(uint2*)(C + base) = *(const uint2*)pk;
            }
        }
        return;
    }

    // block-uniform routing for the flat epilogues
    void* Cb = C0;
    int ld = N, coff = 0;
    if (mode == 2) {
        if (n0 < 2048) { Cb = C0; ld = 2048; coff = 0; }
        else           { Cb = C1; ld = 512;  coff = 2048; }
    } else if (mode == 3) {
        if (n0 < 1024) { Cb = C0; ld = 1024; coff = 0; }
        else           { Cb = C1; ld = 1024; coff = 1024; }
    }
#pragma unroll
    for (int i = 0; i < 4; i++) {
#pragma unroll
        for (int r = 0; r < 4; r++) {
            const int row = m0 + wm + i * 16 + quad * 4 + r;
#pragma unroll
            for (int j = 0; j < 4; j++) {
                const int col = n0 - coff + wn + j * 16 + l16;
                float v = acc[i][j][r];
                if (mode == 1) ((float*)Cb)[(size_t)row * ld + col] = v;
                else ((short*)Cb)[(size_t)row * ld + col] = f2bs(v);
            }
        }
    }
}

// ------------------------------------------------------------- RMSNorm (q)
__global__ __launch_bounds__(256) void rmsnorm_q(const short* __restrict__ X,
                                                 const float* __restrict__ g,
                                                 short* __restrict__ Y, float scale) {
    const int row = blockIdx.x * 4 + (threadIdx.x >> 6);
    const int lane = threadIdx.x & 63;
    const short* p = X + (size_t)row * 128;
    float a = bs2f(p[lane]);
    float c = bs2f(p[lane + 64]);
    float ss = a * a + c * c;
#pragma unroll
    for (int off = 1; off < 64; off <<= 1) ss += __shfl_xor(ss, off);
    float rs = rsqrtf(ss * (1.f / 128.f) + 1e-6f) * scale;
    Y[(size_t)row * 128 + lane] = f2bs(a * rs * g[lane]);
    Y[(size_t)row * 128 + lane + 64] = f2bs(c * rs * g[lane + 64]);
}

// ------------------------------------------------------------- RMSNorm (k)
__global__ __launch_bounds__(256) void rmsnorm_k(const short* __restrict__ KR,
                                                 const short* __restrict__ KN,
                                                 const float* __restrict__ g,
                                                 short* __restrict__ Y) {
    const int rh = blockIdx.x * 4 + (threadIdx.x >> 6);  // m*16+h
    const int m = rh >> 4, h = rh & 15;
    const int lane = threadIdx.x & 63;
    float a = bs2f(KR[(size_t)m * 1024 + h * 64 + lane]);
    float c = bs2f(KN[(size_t)m * 1024 + h * 64 + lane]);
    float ss = a * a + c * c;
#pragma unroll
    for (int off = 1; off < 64; off <<= 1) ss += __shfl_xor(ss, off);
    float rs = rsqrtf(ss * (1.f / 128.f) + 1e-6f);
    Y[(size_t)rh * 128 + lane] = f2bs(a * rs * g[lane]);
    Y[(size_t)rh * 128 + 64 + lane] = f2bs(c * rs * g[lane + 64]);
}

// ------------------------------------------------------ flash attention (causal)
// Q,K,O: bf16 [B,S,H,D]; V pre-transposed: vT[((b*16+h)*128+d)*S + s].
// ONE WAVE PER BLOCK (64 threads), 32 q-rows/wave, 64-key tiles, S^T = K Q^T.
// No __syncthreads anywhere: K/V fragments are loaded directly from global
// (quad-group loads cover each K/V row exactly once, 16B/lane; L1/L2 absorb
// the 4x..64x reuse). P round-trips through wave-private LDS. log2(e) folded
// into q scale -> exp2f softmax.
// Grid: 2048 blocks. blk&7 -> XCD (heuristic), 4 bh per XCD for L2 locality;
// heavy q-waves dispatched first.
#define PSTR 72   // Ps [qrow][key] row stride in shorts

__global__ __launch_bounds__(64) void flash_attn(const short* __restrict__ Q,
                                                 const short* __restrict__ Kb,
                                                 const short* __restrict__ vT,
                                                 short* __restrict__ O, int S) {
    __shared__ short Ps[32 * PSTR];

    const int lane = threadIdx.x & 63;
    const int l16 = lane & 15, quad = lane >> 4;
    const int blk = blockIdx.x;
    const int g = blk >> 3;
    const int bh = (blk & 7) * 4 + (g & 3);     // 4 heads per XCD
    const int b = bh >> 4, h = bh & 15;
    const int qw = 63 - (g >> 2);               // heavy waves first
    const int wq0 = qw * 32;                    // this wave's first q-row

    // Q fragments (B-operand): lane l16 = q-col, quad*8+j = d
    v8s bq[2][4];
#pragma unroll
    for (int qs = 0; qs < 2; qs++) {
        const size_t qbase = ((size_t)(b * S + wq0 + qs * 16 + l16) * 16 + h) * 128;
#pragma unroll
        for (int kc = 0; kc < 4; kc++)
            bq[qs][kc] = *(const v8s*)(Q + qbase + kc * 32 + quad * 8);
    }

    const v4f VZ = {0.f, 0.f, 0.f, 0.f};
    v4f accO[2][8];
#pragma unroll
    for (int qs = 0; qs < 2; qs++)
#pragma unroll
        for (int d = 0; d < 8; d++) accO[qs][d] = VZ;
    float m_i[2] = {-1e30f, -1e30f}, l_i[2] = {0.f, 0.f};

    const short* const kbh = Kb + ((size_t)b * S * 16 + h) * 128;  // + key*2048 + d
    const short* const vbh = vT + (size_t)bh * 128 * S;            // + d*S + key

    const int nkt = ((wq0 + 31) >> 6) + 1;
    for (int kt = 0; kt < nkt; ++kt) {
        const int k0 = kt * 64;

        // S^T tile = K Q^T: rows = keys (quad*4+r), cols = q (l16)
        v4f sc[2][4];
#pragma unroll
        for (int nt = 0; nt < 4; nt++) {
            v8s ak[4];
            const short* krow = kbh + (size_t)(k0 + nt * 16 + l16) * 2048 + quad * 8;
#pragma unroll
            for (int kc = 0; kc < 4; kc++) ak[kc] = *(const v8s*)(krow + kc * 32);
#pragma unroll
            for (int qs = 0; qs < 2; qs++) {
                v4f s = VZ;
#pragma unroll
                for (int kc = 0; kc < 4; kc++) s = MFMA(ak[kc], bq[qs][kc], s);
                sc[qs][nt] = s;
            }
        }

        // causal mask: only the final (diagonal) tile
        if (kt == nkt - 1) {
#pragma unroll
            for (int qs = 0; qs < 2; qs++) {
                const int qrow = wq0 + qs * 16 + l16;
#pragma unroll
                for (int nt = 0; nt < 4; nt++)
#pragma unroll
                    for (int r = 0; r < 4; r++)
                        if (k0 + nt * 16 + quad * 4 + r > qrow) sc[qs][nt][r] = -1e30f;
            }
        }

        // online softmax per q-subtile (lane owns q-col l16)
#pragma unroll
        for (int qs = 0; qs < 2; qs++) {
            float tmax = -1e30f;
#pragma unroll
            for (int nt = 0; nt < 4; nt++)
#pragma unroll
                for (int r = 0; r < 4; r++) tmax = fmaxf(tmax, sc[qs][nt][r]);
            tmax = fmaxf(tmax, __shfl_xor(tmax, 16));
            tmax = fmaxf(tmax, __shfl_xor(tmax, 32));
            const float mnew = fmaxf(m_i[qs], tmax);
            const float alpha = exp2f(m_i[qs] - mnew);
            m_i[qs] = mnew;
            float rsum = 0.f;
#pragma unroll
            for (int nt = 0; nt < 4; nt++) {
                short pk[4];
#pragma unroll
                for (int r = 0; r < 4; r++) {
                    float p = exp2f(sc[qs][nt][r] - mnew);
                    rsum += p;
                    pk[r] = f2bs(p);
                }
                *(uint2*)(&Ps[(qs * 16 + l16) * PSTR + nt * 16 + quad * 4]) =
                    *(const uint2*)pk;
            }
            rsum += __shfl_xor(rsum, 16);
            rsum += __shfl_xor(rsum, 32);
            l_i[qs] = l_i[qs] * alpha + rsum;
            float ar[4];
#pragma unroll
            for (int r = 0; r < 4; r++) ar[r] = __shfl(alpha, quad * 4 + r);
#pragma unroll
            for (int dt = 0; dt < 8; dt++)
#pragma unroll
                for (int r = 0; r < 4; r++) accO[qs][dt][r] *= ar[r];
        }

        // O += P V  (P: A-layout from wave-private LDS; V: direct from global)
        v8s ap[2][2];
#pragma unroll
        for (int qs = 0; qs < 2; qs++)
#pragma unroll
            for (int kc2 = 0; kc2 < 2; kc2++)
                ap[qs][kc2] =
                    *(const v8s*)(&Ps[(qs * 16 + l16) * PSTR + kc2 * 32 + quad * 8]);
#pragma unroll
        for (int dt = 0; dt < 8; dt++) {
            const short* vrow = vbh + (size_t)(dt * 16 + l16) * S + k0 + quad * 8;
#pragma unroll
            for (int kc2 = 0; kc2 < 2; kc2++) {
                v8s bv = *(const v8s*)(vrow + kc2 * 32);
#pragma unroll
                for (int qs = 0; qs < 2; qs++)
                    accO[qs][dt] = MFMA(ap[qs][kc2], bv, accO[qs][dt]);
            }
        }
    }

#pragma unroll
    for (int qs = 0; qs < 2; qs++) {
#pragma unroll
        for (int r = 0; r < 4; r++) {
            const int qg = wq0 + qs * 16 + quad * 4 + r;
            const float inv = 1.f / __shfl(l_i[qs], quad * 4 + r);
            const size_t obase = ((size_t)(b * S + qg) * 16 + h) * 128;
#pragma unroll
            for (int dt = 0; dt < 8; dt++)
                O[obase + dt * 16 + l16] = f2bs(accO[qs][dt][r] * inv);
        }
    }
}

// ---------------------------------------------------------------------------
extern "C" void kernel_launch(void* const* d_in, const int* in_sizes, int n_in,
                              void* d_out, int out_size, void* d_ws, size_t ws_size,
                              hipStream_t stream) {
    (void)in_sizes; (void)n_in; (void)out_size; (void)ws_size;
    const float* x   = (const float*)d_in[0];
    const float* Wq  = (const float*)d_in[1];
    const float* Wkv = (const float*)d_in[2];
    const float* Wkr = (const float*)d_in[3];
    const float* Wkn = (const float*)d_in[4];
    const float* Wv  = (const float*)d_in[5];
    const float* Wo  = (const float*)d_in[6];
    const float* gq  = (const float*)d_in[7];
    const float* gk  = (const float*)d_in[8];

    const int B = 2, S = 2048, HID = 2048, H = 16;
    const int M = B * S;  // 4096

    char* ws = (char*)d_ws;
    size_t off = 0;
    auto alloc = [&](size_t bytes) {
        char* p = ws + off;
        off += (bytes + 255) & ~(size_t)255;
        return p;
    };
    short* xb   = (short*)alloc((size_t)M * HID * 2);
    short* WtA  = (short*)alloc((size_t)2560 * 2048 * 2);  // [Wq^T | Wkv^T]
    short* WtB  = (short*)alloc((size_t)4096 * 512 * 2);   // [Wkr^T | Wkn^T | Wv^T]
    short* Wot  = (short*)alloc((size_t)2048 * 2048 * 2);
    short* qraw = (short*)alloc((size_t)M * 2048 * 2);
    short* qb   = (short*)alloc((size_t)M * 2048 * 2);
    short* lat  = (short*)alloc((size_t)M * 512 * 2);
    short* krr  = (short*)alloc((size_t)M * 1024 * 2);
    short* knr  = (short*)alloc((size_t)M * 1024 * 2);
    short* kb   = (short*)alloc((size_t)M * 2048 * 2);
    short* vT   = (short*)alloc((size_t)M * 2048 * 2);  // [B*H][128][S]
    short* ob   = qraw;  // qraw dead after rmsnorm_q; reuse for attention output

    to_bf16<<<(M * HID) / 1024, 256, 0, stream>>>(x, xb, M * HID);
    transpose_to_bf16<<<dim3(64, 64), 256, 0, stream>>>(Wq, WtA, 2048, 2048);
    transpose_to_bf16<<<dim3(16, 64), 256, 0, stream>>>(Wkv, WtA + (size_t)2048 * 2048, 2048, 512);
    transpose_to_bf16<<<dim3(32, 16), 256, 0, stream>>>(Wkr, WtB, 512, 1024);
    transpose_to_bf16<<<dim3(32, 16), 256, 0, stream>>>(Wkn, WtB + (size_t)1024 * 512, 512, 1024);
    transpose_to_bf16<<<dim3(64, 16), 256, 0, stream>>>(Wv, WtB + (size_t)2048 * 512, 512, 2048);
    transpose_to_bf16<<<dim3(64, 64), 256, 0, stream>>>(Wo, Wot, 2048, 2048);

    // GEMM-A: x @ [Wq | Wkv] -> qraw (bf16) + lat (bf16)
    gemm_bt<<<dim3(2560 / 128, M / 128), 256, 0, stream>>>(
        xb, WtA, qraw, lat, nullptr, M, 2560, 2048, 2);
    // q = rmsnorm(qraw) * gq * (1/sqrt(128)) * log2(e)  [exp2 softmax domain]
    rmsnorm_q<<<(M * H) / 4, 256, 0, stream>>>(
        qraw, gq, qb, 0.08838834764831845f * 1.4426950408889634f);

    // GEMM-B: lat @ [Wkr | Wkn | Wv] -> krr, knr, vT(transposed)
    gemm_bt<<<dim3(4096 / 128, M / 128), 256, 0, stream>>>(
        lat, WtB, krr, knr, vT, M, 4096, 512, 3);
    rmsnorm_k<<<(M * H) / 4, 256, 0, stream>>>(krr, knr, gk, kb);

    // causal SDPA: one wave (32 q-rows) per block, no barriers
    flash_attn<<<dim3(64 * 32), 64, 0, stream>>>(qb, kb, vT, ob, S);

    // GEMM-C: out = o @ Wo (fp32)
    gemm_bt<<<dim3(2048 / 128, M / 128), 256, 0, stream>>>(
        ob, Wot, d_out, nullptr, nullptr, M, 2048, 2048, 1);
}